// Round 7
// baseline (69.307 us; speedup 1.0000x reference)
//
#include <hip/hip_runtime.h>

#define BOUNDING_PERC 0.05f

typedef float  f32x4 __attribute__((ext_vector_type(4)));
typedef float  f32x2 __attribute__((ext_vector_type(2)));

// ---------------------------------------------------------------------------
// Prep: own_nei[pos[j]] = {owners[j], neighbours[j]}
// own_nei pre-filled with -1 (hipMemsetAsync 0xFF) as "no fixup" sentinel.
// ---------------------------------------------------------------------------
__global__ __launch_bounds__(256) void scatter_on_kernel(
    const int* __restrict__ pos, const int* __restrict__ own,
    const int* __restrict__ nei, int2* __restrict__ own_nei, int nb)
{
    int j = blockIdx.x * blockDim.x + threadIdx.x;
    if (j < nb) {
        int2 v; v.x = own[j]; v.y = nei[j];
        own_nei[pos[j]] = v;
    }
}

// ---------------------------------------------------------------------------
// Fused kernel, barrier-free, 2 faces per thread.
//  - wave-private 128-face window: wave stages 1152 floats of source into its
//    own LDS region (4x dwordx4 + 1x dwordx2 per lane, all coalesced, nt)
//  - NO __syncthreads anywhere (total_faces % 128 == 0 -> windows all-valid)
//  - own/nei as one int2 coalesced load per face
//  - the only dependent gathers (ucenters) issue before the dot; their
//    latency hides under 90 FMAs
//  - nt loads on streams (no reuse), nt store on out; uc/own_nei cached
// ---------------------------------------------------------------------------
__global__ __launch_bounds__(256) void fused_kernel(
    const f32x4* __restrict__ k4,      // (b*nfaces) float4's
    const f32x4* __restrict__ s4,      // (b*nfaces*9/4) float4's
    const float* __restrict__ W,       // [4][9]
    const float* __restrict__ bias,    // [9]
    const int2*  __restrict__ own_nei, // (nfaces), x=-1 => no fixup
    const float* __restrict__ uc,      // (b*ncells)
    float*       __restrict__ out,     // (b*nfaces)
    int nfaces, int ncells, int total_faces)
{
    __shared__ float smem[4 * 1152];           // 4 waves * 128 faces * 9 f32
    const int tid  = threadIdx.x;
    const int wv   = tid >> 6;
    const int lane = tid & 63;
    float* mysm = smem + wv * 1152;            // wave-private region

    const int gw = (blockIdx.x << 9) + (wv << 7);   // wave face base
    if (gw >= total_faces) return;             // whole-wave tail guard

    // ---- streaming burst (all coalesced, non-temporal) ----
    const f32x4* sb = s4 + ((size_t)gw * 9) / 4;    // gw%128==0 -> exact
    f32x4 a0 = __builtin_nontemporal_load(sb + lane);
    f32x4 a1 = __builtin_nontemporal_load(sb + lane + 64);
    f32x4 a2 = __builtin_nontemporal_load(sb + lane + 128);
    f32x4 a3 = __builtin_nontemporal_load(sb + lane + 192);
    const f32x2* sb2 = reinterpret_cast<const f32x2*>(sb);
    f32x2 a4 = __builtin_nontemporal_load(sb2 + 512 + lane);
    f32x4 kv0 = __builtin_nontemporal_load(k4 + gw + lane);
    f32x4 kv1 = __builtin_nontemporal_load(k4 + gw + 64 + lane);

    const int g0 = gw + lane;
    const int g1 = gw + 64 + lane;
    const int bb0 = g0 / nfaces;  const int f0 = g0 - bb0 * nfaces;
    const int bb1 = g1 / nfaces;  const int f1 = g1 - bb1 * nfaces;
    const int2 on0 = own_nei[f0];              // coalesced 8B
    const int2 on1 = own_nei[f1];

    // ---- stage into wave-private LDS ----
    f32x4* m4 = reinterpret_cast<f32x4*>(mysm);
    m4[lane]       = a0;
    m4[lane + 64]  = a1;
    m4[lane + 128] = a2;
    m4[lane + 192] = a3;
    f32x2* m2 = reinterpret_cast<f32x2*>(mysm);
    m2[512 + lane] = a4;

    // ---- dependent gathers issued early; latency hides under the dots ----
    float o0 = 0.0f, n0 = 0.0f, o1 = 0.0f, n1 = 0.0f;
    const bool lim0 = (on0.x >= 0);
    const bool lim1 = (on1.x >= 0);
    if (lim0) {
        const float* ucb = uc + (size_t)bb0 * ncells;
        o0 = ucb[on0.x]; n0 = ucb[on0.y];
    }
    if (lim1) {
        const float* ucb = uc + (size_t)bb1 * ncells;
        o1 = ucb[on1.x]; n1 = ucb[on1.y];
    }

    // ---- uniform weights -> SGPRs ----
    float Wr[4][9];
#pragma unroll
    for (int i = 0; i < 4; ++i)
#pragma unroll
        for (int s = 0; s < 9; ++s)
            Wr[i][s] = W[i * 9 + s];
    float br[9];
#pragma unroll
    for (int s = 0; s < 9; ++s) br[s] = bias[s];

    // ---- two dots (stride-9 LDS reads: gcd(9,32)=1, conflict-free) ----
    const float* S0 = mysm + lane * 9;
    const float* S1 = mysm + (64 + lane) * 9;
    float acc0 = 0.0f, acc1 = 0.0f;
#pragma unroll
    for (int s = 0; s < 9; ++s) {
        float c0 = br[s];
        c0 = fmaf(kv0.x, Wr[0][s], c0);
        c0 = fmaf(kv0.y, Wr[1][s], c0);
        c0 = fmaf(kv0.z, Wr[2][s], c0);
        c0 = fmaf(kv0.w, Wr[3][s], c0);
        acc0 = fmaf(c0, S0[s], acc0);
        float c1 = br[s];
        c1 = fmaf(kv1.x, Wr[0][s], c1);
        c1 = fmaf(kv1.y, Wr[1][s], c1);
        c1 = fmaf(kv1.z, Wr[2][s], c1);
        c1 = fmaf(kv1.w, Wr[3][s], c1);
        acc1 = fmaf(c1, S1[s], acc1);
    }

    // ---- bounded fixups ----
    float res0 = acc0;
    if (lim0) {
        float smax = fmaxf(o0, n0), smin = fminf(o0, n0);
        float flux = 0.5f * (o0 + n0);
        float up   = (flux >= 0.0f) ? o0 : n0;
        float hi   = smax + BOUNDING_PERC * fabsf(smax);
        float lo   = smin - BOUNDING_PERC * fabsf(smin);
        res0 = (acc0 >= lo && acc0 <= hi) ? acc0 : up;
    }
    float res1 = acc1;
    if (lim1) {
        float smax = fmaxf(o1, n1), smin = fminf(o1, n1);
        float flux = 0.5f * (o1 + n1);
        float up   = (flux >= 0.0f) ? o1 : n1;
        float hi   = smax + BOUNDING_PERC * fabsf(smax);
        float lo   = smin - BOUNDING_PERC * fabsf(smin);
        res1 = (acc1 >= lo && acc1 <= hi) ? acc1 : up;
    }
    __builtin_nontemporal_store(res0, out + g0);
    __builtin_nontemporal_store(res1, out + g1);
}

// ---------------------------------------------------------------------------
// Fallback pass-1/pass-2 (used only if ws_size is too small)
// ---------------------------------------------------------------------------
__global__ __launch_bounds__(256) void ufaces_kernel(
    const float4* __restrict__ k4, const float4* __restrict__ s4,
    const float* __restrict__ W, const float* __restrict__ bias,
    float* __restrict__ out)
{
    __shared__ float s_src[2304];
    const int tid = threadIdx.x;
    const int base_face = blockIdx.x << 8;
    {
        const float4* src_blk = s4 + ((size_t)base_face * 9) / 4;
        float4* sm4 = reinterpret_cast<float4*>(s_src);
        sm4[tid]       = src_blk[tid];
        sm4[tid + 256] = src_blk[tid + 256];
        if (tid < 64) sm4[tid + 512] = src_blk[tid + 512];
    }
    float Wr[4][9];
#pragma unroll
    for (int i = 0; i < 4; ++i)
#pragma unroll
        for (int s = 0; s < 9; ++s) Wr[i][s] = W[i * 9 + s];
    float br[9];
#pragma unroll
    for (int s = 0; s < 9; ++s) br[s] = bias[s];
    const float4 kv = k4[base_face + tid];
    __syncthreads();
    const float* S = &s_src[tid * 9];
    float acc = 0.0f;
#pragma unroll
    for (int s = 0; s < 9; ++s) {
        float c = br[s];
        c = fmaf(kv.x, Wr[0][s], c);
        c = fmaf(kv.y, Wr[1][s], c);
        c = fmaf(kv.z, Wr[2][s], c);
        c = fmaf(kv.w, Wr[3][s], c);
        acc = fmaf(c, S[s], acc);
    }
    out[base_face + tid] = acc;
}

__global__ __launch_bounds__(256) void bound_kernel(
    const float* __restrict__ uc, const int* __restrict__ pos,
    const int* __restrict__ own, const int* __restrict__ nei,
    float* __restrict__ out, int nb, int nfaces, int ncells, int nbatch)
{
    int idx = blockIdx.x * blockDim.x + threadIdx.x;
    if (idx >= nbatch * nb) return;
    int j  = idx % nb;
    int bb = idx / nb;
    int p = pos[j];
    float uf = out[bb * nfaces + p];
    float o  = uc[bb * ncells + own[j]];
    float n  = uc[bb * ncells + nei[j]];
    float smax = fmaxf(o, n), smin = fminf(o, n);
    float flux = 0.5f * (o + n);
    float up   = (flux >= 0.0f) ? o : n;
    float hi   = smax + BOUNDING_PERC * fabsf(smax);
    float lo   = smin - BOUNDING_PERC * fabsf(smin);
    bool valid = (uf >= lo) && (uf <= hi);
    out[bb * nfaces + p] = valid ? uf : up;
}

extern "C" void kernel_launch(void* const* d_in, const int* in_sizes, int n_in,
                              void* d_out, int out_size, void* d_ws, size_t ws_size,
                              hipStream_t stream)
{
    const float* kernel_in  = (const float*)d_in[0];  // (b, nfaces, 4)
    const float* source     = (const float*)d_in[1];  // (b, nfaces, 3, 3)
    const float* ucenters   = (const float*)d_in[2];  // (b, ncells)
    const float* W          = (const float*)d_in[3];  // (4, 9)
    const float* bias       = (const float*)d_in[4];  // (9,)
    const int*   positions  = (const int*)d_in[5];    // (nb,)
    const int*   owners     = (const int*)d_in[6];    // (nb,)
    const int*   neighbours = (const int*)d_in[7];    // (nb,)
    float*       out        = (float*)d_out;          // (b, nfaces)

    const int b      = 4;
    const int in_dim = 4;
    const int nfaces = in_sizes[0] / (b * in_dim);
    const int ncells = in_sizes[2] / b;
    const int nb     = in_sizes[5];
    const int total_faces = b * nfaces;               // 4,000,000 (%128==0)

    if (ws_size >= (size_t)nfaces * sizeof(int2)) {
        int2* own_nei = (int2*)d_ws;
        // sentinel: own_nei[f].x = -1
        hipMemsetAsync(own_nei, 0xFF, (size_t)nfaces * sizeof(int2), stream);
        scatter_on_kernel<<<(nb + 255) / 256, 256, 0, stream>>>(
            positions, owners, neighbours, own_nei, nb);

        const int faces_per_block = 512;
        const int grid = (total_faces + faces_per_block - 1) / faces_per_block;
        fused_kernel<<<grid, 256, 0, stream>>>(
            (const f32x4*)kernel_in, (const f32x4*)source, W, bias,
            (const int2*)own_nei, ucenters, out, nfaces, ncells, total_faces);
    } else {
        ufaces_kernel<<<total_faces / 256, 256, 0, stream>>>(
            (const float4*)kernel_in, (const float4*)source, W, bias, out);
        int total = b * nb;
        bound_kernel<<<(total + 255) / 256, 256, 0, stream>>>(
            ucenters, positions, owners, neighbours, out, nb, nfaces, ncells, b);
    }
}

// Round 8
// 68.796 us; speedup vs baseline: 1.0074x; 1.0074x over previous
//
#include <hip/hip_runtime.h>

#define BOUNDING_PERC 0.05f

typedef float  f32x4 __attribute__((ext_vector_type(4)));
typedef float  f32x2 __attribute__((ext_vector_type(2)));

// ---------------------------------------------------------------------------
// init: mask[0..nwords*4) = 0   (coalesced dword stores; ~1 MB -> ~1 us)
// ---------------------------------------------------------------------------
__global__ __launch_bounds__(256) void init_mask_kernel(
    unsigned int* __restrict__ mask4, int nwords)
{
    int i = blockIdx.x * blockDim.x + threadIdx.x;
    if (i < nwords) mask4[i] = 0u;
}

// ---------------------------------------------------------------------------
// Prep: mask[pos[j]] = 1; own_f[pos[j]] = owners[j]; nei_f[pos[j]] = neighbours[j]
// own_f / nei_f need NO init: read only where mask != 0.
// ---------------------------------------------------------------------------
__global__ __launch_bounds__(256) void scatter_on_kernel(
    const int* __restrict__ pos, const int* __restrict__ own,
    const int* __restrict__ nei,
    int* __restrict__ own_f, int* __restrict__ nei_f,
    unsigned char* __restrict__ mask, int nb)
{
    int j = blockIdx.x * blockDim.x + threadIdx.x;
    if (j < nb) {
        int p = pos[j];
        own_f[p] = own[j];
        nei_f[p] = nei[j];
        mask[p]  = 1;
    }
}

// ---------------------------------------------------------------------------
// Fused kernel, barrier-free, 2 faces per thread (R7 body + mask gating).
//  - wave-private 128-face LDS window; NO __syncthreads anywhere
//  - nt loads on source/kernel streams, nt store on out (no L2 pollution;
//    keeps ucenters L2-resident for the gathers)
//  - mask byte gates the own_f/nei_f loads and the uc gathers
// ---------------------------------------------------------------------------
__global__ __launch_bounds__(256) void fused_kernel(
    const f32x4* __restrict__ k4,      // (b*nfaces) float4's
    const f32x4* __restrict__ s4,      // (b*nfaces*9/4) float4's
    const float* __restrict__ W,       // [4][9]
    const float* __restrict__ bias,    // [9]
    const unsigned char* __restrict__ mask, // (nfaces), 0 = no fixup
    const int*   __restrict__ own_f,   // (nfaces), valid where mask
    const int*   __restrict__ nei_f,   // (nfaces), valid where mask
    const float* __restrict__ uc,      // (b*ncells)
    float*       __restrict__ out,     // (b*nfaces)
    int nfaces, int ncells, int total_faces)
{
    __shared__ float smem[4 * 1152];           // 4 waves * 128 faces * 9 f32
    const int tid  = threadIdx.x;
    const int wv   = tid >> 6;
    const int lane = tid & 63;
    float* mysm = smem + wv * 1152;            // wave-private region

    const int gw = (blockIdx.x << 9) + (wv << 7);   // wave face base
    if (gw >= total_faces) return;             // whole-wave tail guard

    // ---- streaming burst (all coalesced, non-temporal) ----
    const f32x4* sb = s4 + ((size_t)gw * 9) / 4;    // gw%128==0 -> exact
    f32x4 a0 = __builtin_nontemporal_load(sb + lane);
    f32x4 a1 = __builtin_nontemporal_load(sb + lane + 64);
    f32x4 a2 = __builtin_nontemporal_load(sb + lane + 128);
    f32x4 a3 = __builtin_nontemporal_load(sb + lane + 192);
    const f32x2* sb2 = reinterpret_cast<const f32x2*>(sb);
    f32x2 a4 = __builtin_nontemporal_load(sb2 + 512 + lane);
    f32x4 kv0 = __builtin_nontemporal_load(k4 + gw + lane);
    f32x4 kv1 = __builtin_nontemporal_load(k4 + gw + 64 + lane);

    const int g0 = gw + lane;
    const int g1 = gw + 64 + lane;
    const int bb0 = g0 / nfaces;  const int f0 = g0 - bb0 * nfaces;
    const int bb1 = g1 / nfaces;  const int f1 = g1 - bb1 * nfaces;
    const bool lim0 = (mask[f0] != 0);         // coalesced byte loads
    const bool lim1 = (mask[f1] != 0);

    // ---- stage into wave-private LDS ----
    f32x4* m4 = reinterpret_cast<f32x4*>(mysm);
    m4[lane]       = a0;
    m4[lane + 64]  = a1;
    m4[lane + 128] = a2;
    m4[lane + 192] = a3;
    f32x2* m2 = reinterpret_cast<f32x2*>(mysm);
    m2[512 + lane] = a4;

    // ---- gated gathers issued early; latency hides under the dots ----
    float o0 = 0.0f, n0 = 0.0f, o1 = 0.0f, n1 = 0.0f;
    if (lim0) {
        const float* ucb = uc + (size_t)bb0 * ncells;
        o0 = ucb[own_f[f0]]; n0 = ucb[nei_f[f0]];
    }
    if (lim1) {
        const float* ucb = uc + (size_t)bb1 * ncells;
        o1 = ucb[own_f[f1]]; n1 = ucb[nei_f[f1]];
    }

    // ---- uniform weights -> SGPRs ----
    float Wr[4][9];
#pragma unroll
    for (int i = 0; i < 4; ++i)
#pragma unroll
        for (int s = 0; s < 9; ++s)
            Wr[i][s] = W[i * 9 + s];
    float br[9];
#pragma unroll
    for (int s = 0; s < 9; ++s) br[s] = bias[s];

    // ---- two dots (stride-9 LDS reads: gcd(9,32)=1, conflict-free) ----
    const float* S0 = mysm + lane * 9;
    const float* S1 = mysm + (64 + lane) * 9;
    float acc0 = 0.0f, acc1 = 0.0f;
#pragma unroll
    for (int s = 0; s < 9; ++s) {
        float c0 = br[s];
        c0 = fmaf(kv0.x, Wr[0][s], c0);
        c0 = fmaf(kv0.y, Wr[1][s], c0);
        c0 = fmaf(kv0.z, Wr[2][s], c0);
        c0 = fmaf(kv0.w, Wr[3][s], c0);
        acc0 = fmaf(c0, S0[s], acc0);
        float c1 = br[s];
        c1 = fmaf(kv1.x, Wr[0][s], c1);
        c1 = fmaf(kv1.y, Wr[1][s], c1);
        c1 = fmaf(kv1.z, Wr[2][s], c1);
        c1 = fmaf(kv1.w, Wr[3][s], c1);
        acc1 = fmaf(c1, S1[s], acc1);
    }

    // ---- bounded fixups ----
    float res0 = acc0;
    if (lim0) {
        float smax = fmaxf(o0, n0), smin = fminf(o0, n0);
        float flux = 0.5f * (o0 + n0);
        float up   = (flux >= 0.0f) ? o0 : n0;
        float hi   = smax + BOUNDING_PERC * fabsf(smax);
        float lo   = smin - BOUNDING_PERC * fabsf(smin);
        res0 = (acc0 >= lo && acc0 <= hi) ? acc0 : up;
    }
    float res1 = acc1;
    if (lim1) {
        float smax = fmaxf(o1, n1), smin = fminf(o1, n1);
        float flux = 0.5f * (o1 + n1);
        float up   = (flux >= 0.0f) ? o1 : n1;
        float hi   = smax + BOUNDING_PERC * fabsf(smax);
        float lo   = smin - BOUNDING_PERC * fabsf(smin);
        res1 = (acc1 >= lo && acc1 <= hi) ? acc1 : up;
    }
    __builtin_nontemporal_store(res0, out + g0);
    __builtin_nontemporal_store(res1, out + g1);
}

// ---------------------------------------------------------------------------
// Fallback pass-1/pass-2 (used only if ws_size is too small)
// ---------------------------------------------------------------------------
__global__ __launch_bounds__(256) void ufaces_kernel(
    const float4* __restrict__ k4, const float4* __restrict__ s4,
    const float* __restrict__ W, const float* __restrict__ bias,
    float* __restrict__ out)
{
    __shared__ float s_src[2304];
    const int tid = threadIdx.x;
    const int base_face = blockIdx.x << 8;
    {
        const float4* src_blk = s4 + ((size_t)base_face * 9) / 4;
        float4* sm4 = reinterpret_cast<float4*>(s_src);
        sm4[tid]       = src_blk[tid];
        sm4[tid + 256] = src_blk[tid + 256];
        if (tid < 64) sm4[tid + 512] = src_blk[tid + 512];
    }
    float Wr[4][9];
#pragma unroll
    for (int i = 0; i < 4; ++i)
#pragma unroll
        for (int s = 0; s < 9; ++s) Wr[i][s] = W[i * 9 + s];
    float br[9];
#pragma unroll
    for (int s = 0; s < 9; ++s) br[s] = bias[s];
    const float4 kv = k4[base_face + tid];
    __syncthreads();
    const float* S = &s_src[tid * 9];
    float acc = 0.0f;
#pragma unroll
    for (int s = 0; s < 9; ++s) {
        float c = br[s];
        c = fmaf(kv.x, Wr[0][s], c);
        c = fmaf(kv.y, Wr[1][s], c);
        c = fmaf(kv.z, Wr[2][s], c);
        c = fmaf(kv.w, Wr[3][s], c);
        acc = fmaf(c, S[s], acc);
    }
    out[base_face + tid] = acc;
}

__global__ __launch_bounds__(256) void bound_kernel(
    const float* __restrict__ uc, const int* __restrict__ pos,
    const int* __restrict__ own, const int* __restrict__ nei,
    float* __restrict__ out, int nb, int nfaces, int ncells, int nbatch)
{
    int idx = blockIdx.x * blockDim.x + threadIdx.x;
    if (idx >= nbatch * nb) return;
    int j  = idx % nb;
    int bb = idx / nb;
    int p = pos[j];
    float uf = out[bb * nfaces + p];
    float o  = uc[bb * ncells + own[j]];
    float n  = uc[bb * ncells + nei[j]];
    float smax = fmaxf(o, n), smin = fminf(o, n);
    float flux = 0.5f * (o + n);
    float up   = (flux >= 0.0f) ? o : n;
    float hi   = smax + BOUNDING_PERC * fabsf(smax);
    float lo   = smin - BOUNDING_PERC * fabsf(smin);
    bool valid = (uf >= lo) && (uf <= hi);
    out[bb * nfaces + p] = valid ? uf : up;
}

extern "C" void kernel_launch(void* const* d_in, const int* in_sizes, int n_in,
                              void* d_out, int out_size, void* d_ws, size_t ws_size,
                              hipStream_t stream)
{
    const float* kernel_in  = (const float*)d_in[0];  // (b, nfaces, 4)
    const float* source     = (const float*)d_in[1];  // (b, nfaces, 3, 3)
    const float* ucenters   = (const float*)d_in[2];  // (b, ncells)
    const float* W          = (const float*)d_in[3];  // (4, 9)
    const float* bias       = (const float*)d_in[4];  // (9,)
    const int*   positions  = (const int*)d_in[5];    // (nb,)
    const int*   owners     = (const int*)d_in[6];    // (nb,)
    const int*   neighbours = (const int*)d_in[7];    // (nb,)
    float*       out        = (float*)d_out;          // (b, nfaces)

    const int b      = 4;
    const int in_dim = 4;
    const int nfaces = in_sizes[0] / (b * in_dim);
    const int ncells = in_sizes[2] / b;
    const int nb     = in_sizes[5];
    const int total_faces = b * nfaces;               // 4,000,000 (%128==0)

    // workspace layout: own_f (nfaces int) | nei_f (nfaces int) | mask (nfaces bytes)
    const size_t need = 2 * (size_t)nfaces * sizeof(int) + (size_t)nfaces;
    if (ws_size >= need) {
        int* own_f = (int*)d_ws;
        int* nei_f = own_f + nfaces;
        unsigned char* mask = (unsigned char*)(nei_f + nfaces);

        const int nwords = nfaces / 4;         // 1e6 % 4 == 0
        init_mask_kernel<<<(nwords + 255) / 256, 256, 0, stream>>>(
            (unsigned int*)mask, nwords);
        scatter_on_kernel<<<(nb + 255) / 256, 256, 0, stream>>>(
            positions, owners, neighbours, own_f, nei_f, mask, nb);

        const int faces_per_block = 512;
        const int grid = (total_faces + faces_per_block - 1) / faces_per_block;
        fused_kernel<<<grid, 256, 0, stream>>>(
            (const f32x4*)kernel_in, (const f32x4*)source, W, bias,
            mask, own_f, nei_f, ucenters, out, nfaces, ncells, total_faces);
    } else {
        ufaces_kernel<<<total_faces / 256, 256, 0, stream>>>(
            (const float4*)kernel_in, (const float4*)source, W, bias, out);
        int total = b * nb;
        bound_kernel<<<(total + 255) / 256, 256, 0, stream>>>(
            ucenters, positions, owners, neighbours, out, nb, nfaces, ncells, b);
    }
}

// Round 9
// 60.003 us; speedup vs baseline: 1.1551x; 1.1465x over previous
//
#include <hip/hip_runtime.h>

#define BOUNDING_PERC 0.05f

// ---------------------------------------------------------------------------
// init: mask words = 0  (1 MB of coalesced dword stores, ~1-2 us; avoids the
// slow rocclr fillBuffer dispatch entirely)
// ---------------------------------------------------------------------------
__global__ __launch_bounds__(256) void init_mask_kernel(
    unsigned int* __restrict__ mask4, int nwords)
{
    int i = blockIdx.x * blockDim.x + threadIdx.x;
    if (i < nwords) mask4[i] = 0u;
}

// ---------------------------------------------------------------------------
// Prep: mask[pos[j]] = 1; own_f[pos[j]] = owners[j]; nei_f[pos[j]] = neighbours[j]
// own_f / nei_f need NO init: read only where mask != 0.
// ---------------------------------------------------------------------------
__global__ __launch_bounds__(256) void scatter_on_kernel(
    const int* __restrict__ pos, const int* __restrict__ own,
    const int* __restrict__ nei,
    int* __restrict__ own_f, int* __restrict__ nei_f,
    unsigned char* __restrict__ mask, int nb)
{
    int j = blockIdx.x * blockDim.x + threadIdx.x;
    if (j < nb) {
        int p = pos[j];
        own_f[p] = own[j];
        nei_f[p] = nei[j];
        mask[p]  = 1;
    }
}

// ---------------------------------------------------------------------------
// Fused kernel = R6's proven body (1 face/thread, wave-private LDS staging,
// barrier-free, regular cached loads) + mask gating of index/gather loads.
//  - each wave stages only its own 64 faces (576 floats) and reads only its
//    own region -> NO __syncthreads anywhere
//  - mask byte (coalesced) gates own_f/nei_f loads and uc gathers; for this
//    input mask is wave-uniform nearly everywhere -> no divergence cost
//  - gathers issue BEFORE the 45-FMA dot so latency hides under compute
// ---------------------------------------------------------------------------
__global__ __launch_bounds__(256) void fused_kernel(
    const float4* __restrict__ k4,     // (b*nfaces) float4's
    const float4* __restrict__ s4,     // (b*nfaces*9/4) float4's
    const float*  __restrict__ W,      // [4][9]
    const float*  __restrict__ bias,   // [9]
    const unsigned char* __restrict__ mask, // (nfaces), 0 = no fixup
    const int*    __restrict__ own_f,  // (nfaces), valid where mask
    const int*    __restrict__ nei_f,  // (nfaces), valid where mask
    const float*  __restrict__ uc,     // (b*ncells)
    float*        __restrict__ out,    // (b*nfaces)
    int nfaces, int ncells)
{
    __shared__ float smem[2304];               // 4 waves * 576 floats
    const int tid  = threadIdx.x;
    const int wv   = tid >> 6;
    const int lane = tid & 63;
    float* mysm = smem + wv * 576;             // wave-private region

    const int gbase = blockIdx.x << 8;         // block face base
    const int gw    = gbase + (wv << 6);       // wave face base
    const int g     = gw + lane;               // global face index

    // ---- streaming burst (all coalesced, cached) ----
    const float4* sb  = s4 + ((size_t)gw * 9) / 4;   // gw*9 divisible by 4
    const float*  sbf = reinterpret_cast<const float*>(sb);
    float4 a0 = sb[lane];                      // source floats [0..255]
    float4 a1 = sb[lane + 64];                 // source floats [256..511]
    float  a2 = sbf[512 + lane];               // source floats [512..575]
    float4 kv = k4[g];

    const int bb = g / nfaces;                 // per-thread batch index
    const int f  = g - bb * nfaces;            // in-batch face index
    const bool lim = (mask[f] != 0);           // coalesced byte load

    // ---- stage into wave-private LDS ----
    float4* mysm4 = reinterpret_cast<float4*>(mysm);
    mysm4[lane]      = a0;
    mysm4[lane + 64] = a1;
    mysm[512 + lane] = a2;

    // ---- gated gathers issued early; latency hides under the dot ----
    float o = 0.0f, n = 0.0f;
    if (lim) {
        const float* ucb = uc + (size_t)bb * ncells;
        o = ucb[own_f[f]];
        n = ucb[nei_f[f]];
    }

    // ---- uniform weights -> SGPRs ----
    float Wr[4][9];
#pragma unroll
    for (int i = 0; i < 4; ++i)
#pragma unroll
        for (int s = 0; s < 9; ++s)
            Wr[i][s] = W[i * 9 + s];
    float br[9];
#pragma unroll
    for (int s = 0; s < 9; ++s) br[s] = bias[s];

    // ---- dot (stride-9 LDS reads: gcd(9,32)=1, conflict-free) ----
    const float* S = mysm + lane * 9;
    float acc = 0.0f;
#pragma unroll
    for (int s = 0; s < 9; ++s) {
        float c = br[s];
        c = fmaf(kv.x, Wr[0][s], c);
        c = fmaf(kv.y, Wr[1][s], c);
        c = fmaf(kv.z, Wr[2][s], c);
        c = fmaf(kv.w, Wr[3][s], c);
        acc = fmaf(c, S[s], acc);
    }

    float res = acc;
    if (lim) {
        float smax = fmaxf(o, n), smin = fminf(o, n);
        float flux = 0.5f * (o + n);
        float up   = (flux >= 0.0f) ? o : n;
        float hi   = smax + BOUNDING_PERC * fabsf(smax);
        float lo   = smin - BOUNDING_PERC * fabsf(smin);
        bool valid = (acc >= lo) && (acc <= hi);
        res = valid ? acc : up;
    }
    out[g] = res;
}

// ---------------------------------------------------------------------------
// Fallback pass-1/pass-2 (used only if ws_size is too small)
// ---------------------------------------------------------------------------
__global__ __launch_bounds__(256) void ufaces_kernel(
    const float4* __restrict__ k4, const float4* __restrict__ s4,
    const float* __restrict__ W, const float* __restrict__ bias,
    float* __restrict__ out)
{
    __shared__ float s_src[2304];
    const int tid = threadIdx.x;
    const int base_face = blockIdx.x << 8;
    {
        const float4* src_blk = s4 + ((size_t)base_face * 9) / 4;
        float4* sm4 = reinterpret_cast<float4*>(s_src);
        sm4[tid]       = src_blk[tid];
        sm4[tid + 256] = src_blk[tid + 256];
        if (tid < 64) sm4[tid + 512] = src_blk[tid + 512];
    }
    float Wr[4][9];
#pragma unroll
    for (int i = 0; i < 4; ++i)
#pragma unroll
        for (int s = 0; s < 9; ++s) Wr[i][s] = W[i * 9 + s];
    float br[9];
#pragma unroll
    for (int s = 0; s < 9; ++s) br[s] = bias[s];
    const float4 kv = k4[base_face + tid];
    __syncthreads();
    const float* S = &s_src[tid * 9];
    float acc = 0.0f;
#pragma unroll
    for (int s = 0; s < 9; ++s) {
        float c = br[s];
        c = fmaf(kv.x, Wr[0][s], c);
        c = fmaf(kv.y, Wr[1][s], c);
        c = fmaf(kv.z, Wr[2][s], c);
        c = fmaf(kv.w, Wr[3][s], c);
        acc = fmaf(c, S[s], acc);
    }
    out[base_face + tid] = acc;
}

__global__ __launch_bounds__(256) void bound_kernel(
    const float* __restrict__ uc, const int* __restrict__ pos,
    const int* __restrict__ own, const int* __restrict__ nei,
    float* __restrict__ out, int nb, int nfaces, int ncells, int nbatch)
{
    int idx = blockIdx.x * blockDim.x + threadIdx.x;
    if (idx >= nbatch * nb) return;
    int j  = idx % nb;
    int bb = idx / nb;
    int p = pos[j];
    float uf = out[bb * nfaces + p];
    float o  = uc[bb * ncells + own[j]];
    float n  = uc[bb * ncells + nei[j]];
    float smax = fmaxf(o, n), smin = fminf(o, n);
    float flux = 0.5f * (o + n);
    float up   = (flux >= 0.0f) ? o : n;
    float hi   = smax + BOUNDING_PERC * fabsf(smax);
    float lo   = smin - BOUNDING_PERC * fabsf(smin);
    bool valid = (uf >= lo) && (uf <= hi);
    out[bb * nfaces + p] = valid ? uf : up;
}

extern "C" void kernel_launch(void* const* d_in, const int* in_sizes, int n_in,
                              void* d_out, int out_size, void* d_ws, size_t ws_size,
                              hipStream_t stream)
{
    const float* kernel_in  = (const float*)d_in[0];  // (b, nfaces, 4)
    const float* source     = (const float*)d_in[1];  // (b, nfaces, 3, 3)
    const float* ucenters   = (const float*)d_in[2];  // (b, ncells)
    const float* W          = (const float*)d_in[3];  // (4, 9)
    const float* bias       = (const float*)d_in[4];  // (9,)
    const int*   positions  = (const int*)d_in[5];    // (nb,)
    const int*   owners     = (const int*)d_in[6];    // (nb,)
    const int*   neighbours = (const int*)d_in[7];    // (nb,)
    float*       out        = (float*)d_out;          // (b, nfaces)

    const int b      = 4;
    const int in_dim = 4;
    const int nfaces = in_sizes[0] / (b * in_dim);
    const int ncells = in_sizes[2] / b;
    const int nb     = in_sizes[5];
    const int total_faces = b * nfaces;               // 4,000,000 (% 256 == 0)

    // workspace layout: own_f (nfaces int) | nei_f (nfaces int) | mask (nfaces B)
    const size_t need = 2 * (size_t)nfaces * sizeof(int) + (size_t)nfaces;
    if (ws_size >= need) {
        int* own_f = (int*)d_ws;
        int* nei_f = own_f + nfaces;
        unsigned char* mask = (unsigned char*)(nei_f + nfaces);

        const int nwords = nfaces / 4;         // 1e6 % 4 == 0
        init_mask_kernel<<<(nwords + 255) / 256, 256, 0, stream>>>(
            (unsigned int*)mask, nwords);
        scatter_on_kernel<<<(nb + 255) / 256, 256, 0, stream>>>(
            positions, owners, neighbours, own_f, nei_f, mask, nb);

        fused_kernel<<<total_faces / 256, 256, 0, stream>>>(
            (const float4*)kernel_in, (const float4*)source, W, bias,
            mask, own_f, nei_f, ucenters, out, nfaces, ncells);
    } else {
        ufaces_kernel<<<total_faces / 256, 256, 0, stream>>>(
            (const float4*)kernel_in, (const float4*)source, W, bias, out);
        int total = b * nb;
        bound_kernel<<<(total + 255) / 256, 256, 0, stream>>>(
            ucenters, positions, owners, neighbours, out, nb, nfaces, ncells, b);
    }
}